// Round 6
// baseline (238.146 us; speedup 1.0000x reference)
//
#include <hip/hip_runtime.h>
#include <math.h>

#define D_    256
#define NE    512
#define NNODE 64
#define NHEAD 4
#define SLOPE 0.2f
#define BTN   65536

typedef __attribute__((ext_vector_type(4))) float f32x4;
typedef __attribute__((ext_vector_type(8))) short s16x8;
typedef unsigned short u16;

__device__ inline u16 f2bf(float x) {
    union { float f; unsigned u; } v; v.f = x;
    unsigned r = v.u + 0x7fff + ((v.u >> 16) & 1);
    return (u16)(r >> 16);
}
__device__ inline float bf2f(u16 b) {
    union { float f; unsigned u; } v; v.u = ((unsigned)b) << 16;
    return v.f;
}

#define GLD16(g, l) __builtin_amdgcn_global_load_lds( \
    (const __attribute__((address_space(1))) void*)(g), \
    (__attribute__((address_space(3))) void*)(l), 16, 0, 0)

// ---------------------------------------------------------------------------
// Parallel deterministic CSR build + log(A0+eps). One block, 512 threads.
// ---------------------------------------------------------------------------
__global__ __launch_bounds__(512) void build_csr(const int* __restrict__ src,
    const int* __restrict__ dst, const float* __restrict__ A0,
    int* __restrict__ csr_off, int* __restrict__ csr_eid, float* __restrict__ logA0)
{
    __shared__ int sS[NE];
    __shared__ int sCnt[NNODE];
    __shared__ int sOf[NNODE + 1];
    const int t = threadIdx.x;
    sS[t] = src[t];
    __syncthreads();
    if (t < NNODE) {
        int c = 0;
        for (int e = 0; e < NE; ++e) c += (sS[e] == t);
        sCnt[t] = c;
    }
    __syncthreads();
    if (t == 0) {
        int run = 0;
        for (int n = 0; n < NNODE; ++n) { sOf[n] = run; run += sCnt[n]; }
        sOf[NNODE] = run;
    }
    __syncthreads();
    {
        int s = sS[t];
        int rank = 0;
        for (int e = 0; e < NE; ++e) rank += (int)((sS[e] == s) && (e < t));
        csr_eid[sOf[s] + rank] = t;                 // stable order within segment
        logA0[t] = logf(A0[s * NNODE + dst[t]] + 1e-8f);
    }
    if (t <= NNODE) csr_off[t] = sOf[t];
}

// ---------------------------------------------------------------------------
// fp32 -> split bf16 (hi + lo), grid-stride over float4s.
// ---------------------------------------------------------------------------
__global__ __launch_bounds__(256) void prep_split(const float* __restrict__ s,
    u16* __restrict__ h, u16* __restrict__ l, int n4)
{
    for (int i = blockIdx.x * 256 + threadIdx.x; i < n4; i += gridDim.x * 256) {
        float4 v = ((const float4*)s)[i];
        u16 h0 = f2bf(v.x), h1 = f2bf(v.y), h2 = f2bf(v.z), h3 = f2bf(v.w);
        ((ushort4*)h)[i] = make_ushort4(h0, h1, h2, h3);
        ((ushort4*)l)[i] = make_ushort4(f2bf(v.x - bf2f(h0)), f2bf(v.y - bf2f(h1)),
                                        f2bf(v.z - bf2f(h2)), f2bf(v.w - bf2f(h3)));
    }
}

// ---------------------------------------------------------------------------
// Split-bf16 MFMA GEMM. FULL: 3-pass (hh+hl+lh, fp32-grade); else 1-pass bf16.
// 128x128 tile, BK=32, 256 threads (4 waves). 1D grid, n-fastest pairing +
// bijective XCD swizzle (nwg=1024 % 8 == 0) for A-tile L2 reuse.
// ---------------------------------------------------------------------------
template<bool FULL, bool OUT_BF16>
__global__ __launch_bounds__(256) void gemm_bf16s(const u16* __restrict__ Ah,
    const u16* __restrict__ Al, const u16* __restrict__ Bh, const u16* __restrict__ Bl,
    void* __restrict__ Cout)
{
    __shared__ u16 sAh[4096], sBh[4096];                 // [128][32], linear
    __shared__ u16 sAl[FULL ? 4096 : 16], sBl[FULL ? 4096 : 16];
    const int t = threadIdx.x, lane = t & 63, wave = t >> 6;
    const int wm = wave >> 1, wn = wave & 1;
    const int bid = blockIdx.x;
    const int swz = (bid & 7) * 128 + (bid >> 3);        // XCD-contiguous
    const int m0 = (swz >> 1) * 128, n0 = (swz & 1) * 128;
    const int fr = lane & 15, kq = (lane >> 4) * 8;

    f32x4 acc[4][4];
    #pragma unroll
    for (int i = 0; i < 4; ++i)
        #pragma unroll
        for (int j = 0; j < 4; ++j) acc[i][j] = 0.f;

    for (int k0 = 0; k0 < D_; k0 += 32) {
        #pragma unroll
        for (int s = 0; s < 2; ++s) {
            const int cb = (s * 4 + wave) * 64;
            const int c  = cb + lane;
            const int row = c >> 2, ks = (c & 3) * 8;
            const size_t ga = (size_t)(m0 + row) * D_ + k0 + ks;
            const size_t gb = (size_t)(n0 + row) * D_ + k0 + ks;
            GLD16(Ah + ga, sAh + cb * 8);
            GLD16(Bh + gb, sBh + cb * 8);
            if (FULL) {
                GLD16(Al + ga, sAl + cb * 8);
                GLD16(Bl + gb, sBl + cb * 8);
            }
        }
        __syncthreads();

        s16x8 fah[4], fal[4];
        #pragma unroll
        for (int mi = 0; mi < 4; ++mi) {
            fah[mi] = *(const s16x8*)(sAh + (wm * 64 + mi * 16 + fr) * 32 + kq);
            if (FULL) fal[mi] = *(const s16x8*)(sAl + (wm * 64 + mi * 16 + fr) * 32 + kq);
        }
        #pragma unroll
        for (int ni = 0; ni < 4; ++ni) {
            s16x8 fbh = *(const s16x8*)(sBh + (wn * 64 + ni * 16 + fr) * 32 + kq);
            s16x8 fbl;
            if (FULL) fbl = *(const s16x8*)(sBl + (wn * 64 + ni * 16 + fr) * 32 + kq);
            #pragma unroll
            for (int mi = 0; mi < 4; ++mi) {
                acc[mi][ni] = __builtin_amdgcn_mfma_f32_16x16x32_bf16(fah[mi], fbh, acc[mi][ni], 0, 0, 0);
                if (FULL) {
                    acc[mi][ni] = __builtin_amdgcn_mfma_f32_16x16x32_bf16(fah[mi], fbl, acc[mi][ni], 0, 0, 0);
                    acc[mi][ni] = __builtin_amdgcn_mfma_f32_16x16x32_bf16(fal[mi], fbh, acc[mi][ni], 0, 0, 0);
                }
            }
        }
        __syncthreads();
    }

    const int fq = (lane >> 4) * 4;   // C/D: col = lane&15, row = (lane>>4)*4 + reg
    #pragma unroll
    for (int mi = 0; mi < 4; ++mi)
        #pragma unroll
        for (int ni = 0; ni < 4; ++ni)
            #pragma unroll
            for (int r = 0; r < 4; ++r) {
                size_t off = (size_t)(m0 + wm * 64 + mi * 16 + fq + r) * D_
                           + n0 + wn * 64 + ni * 16 + fr;
                if (OUT_BF16) ((u16*)Cout)[off] = f2bf(acc[mi][ni][r]);
                else          ((float*)Cout)[off] = acc[mi][ni][r];
            }
}

// ---------------------------------------------------------------------------
// Fused edge scores + segment softmax + aggregation, one block per (bt, head).
// Q fp32 16KB, V bf16 8KB, both XOR-swizzled (linear GLD16 dest + swizzled
// global source + swizzled read index) -> conflict-free LDS reads.
// ---------------------------------------------------------------------------
__global__ __launch_bounds__(256) void fused_edge_agg(
    const float* __restrict__ Xq, const u16* __restrict__ Xvb,
    const int* __restrict__ gsrc, const int* __restrict__ gdst,
    const float* __restrict__ a,
    const float* __restrict__ logA0, const int* __restrict__ csr_off,
    const int* __restrict__ csr_eid,
    u16* __restrict__ Yh, u16* __restrict__ Yl)
{
    __shared__ float sQ[NNODE * 64];      // 16 KB, 16B-chunk c ^= (row&15)
    __shared__ u16   sV[NNODE * 64];      // 8 KB,  16B-chunk c ^= (row&7)
    __shared__ float sE[NE];
    __shared__ float sLog[NE];
    __shared__ int   sPack[NE];           // (src<<8)|dst
    __shared__ int   sEid[NE];
    __shared__ float sDen[NNODE];
    __shared__ int   sOff[NNODE + 1];

    const int t = threadIdx.x;
    const int grp = t >> 4, lg = t & 15;      // 16 groups x 16 lanes
    const int bt = blockIdx.x >> 2, h = blockIdx.x & 3;

    // ---- stage Q/V via global_load_lds, source pre-swizzled (rule #21) ----
    const float* gq = Xq + (size_t)bt * NNODE * D_ + h * 64;
    {
        #pragma unroll
        for (int r = 0; r < 4; ++r) {
            int id = r * 256 + t;
            int row = id >> 4, c = id & 15;
            int csw = c ^ (row & 15);
            GLD16(gq + (size_t)row * D_ + csw * 4, (char*)sQ + id * 16);
        }
    }
    const u16* gv = Xvb + (size_t)bt * NNODE * D_ + h * 64;
    {
        #pragma unroll
        for (int r = 0; r < 2; ++r) {
            int id = r * 256 + t;
            int row = id >> 3, c = id & 7;
            int csw = c ^ (row & 7);
            GLD16(gv + (size_t)row * D_ + csw * 8, (char*)sV + id * 16);
        }
    }
    sPack[t]       = (gsrc[t] << 8)       | gdst[t];
    sPack[t + 256] = (gsrc[t + 256] << 8) | gdst[t + 256];
    sEid[t] = csr_eid[t]; sEid[t + 256] = csr_eid[t + 256];
    sLog[t] = logA0[t];   sLog[t + 256] = logA0[t + 256];
    if (t <= NNODE) sOff[t] = csr_off[t];
    const float4 areg = *(const float4*)&a[h * 64 + lg * 4];
    __syncthreads();   // drains global_load_lds (vmcnt) + lds writes

    // ---- edge scores: group handles 32 edges, 16 lanes x 4 dims ----
    for (int it = 0; it < 32; ++it) {
        int e = grp * 32 + it;
        int pk = sPack[e];
        int s_ = pk >> 8, d_ = pk & 255;
        float4 q = ((const float4*)sQ)[s_ * 16 + (lg ^ (s_ & 15))];
        float4 k = ((const float4*)sQ)[d_ * 16 + (lg ^ (d_ & 15))];
        float x0 = q.x + k.x, x1 = q.y + k.y, x2 = q.z + k.z, x3 = q.w + k.w;
        x0 = x0 > 0.f ? x0 : SLOPE * x0;
        x1 = x1 > 0.f ? x1 : SLOPE * x1;
        x2 = x2 > 0.f ? x2 : SLOPE * x2;
        x3 = x3 > 0.f ? x3 : SLOPE * x3;
        float p = x0 * areg.x + x1 * areg.y + x2 * areg.z + x3 * areg.w;
        p += __shfl_xor(p, 1);
        p += __shfl_xor(p, 2);
        p += __shfl_xor(p, 4);
        p += __shfl_xor(p, 8);
        if (lg == 0) sE[e] = p + sLog[e];
    }
    __syncthreads();

    // ---- segment softmax: 4 threads per node (quad in same wave) ----
    {
        int n = t >> 2, q = t & 3;
        int o0 = sOff[n], o1 = sOff[n + 1];
        float m = -INFINITY;
        for (int i = o0 + q; i < o1; i += 4) m = fmaxf(m, sE[sEid[i]]);
        m = fmaxf(m, __shfl_xor(m, 1));
        m = fmaxf(m, __shfl_xor(m, 2));
        float den = 0.f;
        for (int i = o0 + q; i < o1; i += 4) {
            int e = sEid[i];
            float w = __expf(sE[e] - m);
            den += w;
            sE[e] = w;                        // unnormalized weight
        }
        den += __shfl_xor(den, 1);
        den += __shfl_xor(den, 2);
        if (q == 0) sDen[n] = (o1 > o0) ? 1.f / den : 0.f;
    }
    __syncthreads();

    // ---- aggregate: group owns 4 nodes; scale by 1/den; split-bf16 output ----
    u16* yh = Yh + (size_t)bt * NNODE * D_ + h * 64;
    u16* yl = Yl + (size_t)bt * NNODE * D_ + h * 64;
    #pragma unroll
    for (int j = 0; j < 4; ++j) {
        int n = grp * 4 + j;
        int o0 = sOff[n], o1 = sOff[n + 1];
        float ax = 0.f, ay = 0.f, az = 0.f, aw = 0.f;
        for (int i = o0; i < o1; ++i) {
            int e = sEid[i];
            float w = sE[e];
            int d_ = sPack[e] & 255;
            ushort4 v = *(const ushort4*)&sV[d_ * 64 + (((lg >> 1) ^ (d_ & 7)) << 3)
                                             + ((lg & 1) << 2)];
            ax += w * bf2f(v.x); ay += w * bf2f(v.y);
            az += w * bf2f(v.z); aw += w * bf2f(v.w);
        }
        float inv = sDen[n];
        ax *= inv; ay *= inv; az *= inv; aw *= inv;
        u16 h0 = f2bf(ax), h1 = f2bf(ay), h2 = f2bf(az), h3 = f2bf(aw);
        *(ushort4*)&yh[(size_t)n * D_ + lg * 4] = make_ushort4(h0, h1, h2, h3);
        *(ushort4*)&yl[(size_t)n * D_ + lg * 4] =
            make_ushort4(f2bf(ax - bf2f(h0)), f2bf(ay - bf2f(h1)),
                         f2bf(az - bf2f(h2)), f2bf(aw - bf2f(h3)));
    }
}

// ---------------------------------------------------------------------------
extern "C" void kernel_launch(void* const* d_in, const int* in_sizes, int n_in,
                              void* d_out, int out_size, void* d_ws, size_t ws_size,
                              hipStream_t stream)
{
    const float* H     = (const float*)d_in[0];
    const float* W_lin = (const float*)d_in[1];
    const float* W_val = (const float*)d_in[2];
    const float* a     = (const float*)d_in[3];
    const float* W_out = (const float*)d_in[4];
    const float* A0    = (const float*)d_in[5];
    const int*   src   = (const int*)d_in[6];
    const int*   dst   = (const int*)d_in[7];

    const size_t nX = (size_t)BTN * D_;              // 16777216 elems
    // ws: Hh | Hl | Xq(fp32)  == 134217728 B exactly
    u16*   Hh = (u16*)d_ws;
    u16*   Hl = Hh + nX;
    float* Xq = (float*)(Hl + nX);
    u16*   Yh = Hh;                                  // alias: H dead after GEMM2
    u16*   Yl = Hl;
    u16*   Wouth = (u16*)Xq;                         // alias: Xq dead after fused
    u16*   Woutl = Wouth + D_ * D_;
    if (ws_size < (size_t)134217728) return;

    // d_out scratch until GEMM3: Xv bf16 [0,33.5MB) ; lists/W-splits at +40MB
    u16*   Xvb = (u16*)d_out;
    char*  sc2 = (char*)d_out + (size_t)40 * 1024 * 1024;
    float* logA0   = (float*)sc2;                    // 2 KB
    int*   csr_off = (int*)(sc2 + 4096);
    int*   csr_eid = (int*)(sc2 + 8192);
    u16*   Wlh = (u16*)(sc2 + 16384);                // 128 KB each
    u16*   Wll = Wlh + D_ * D_;
    u16*   Wvh = Wll + D_ * D_;
    u16*   Wvl = Wvh + D_ * D_;

    build_csr<<<1, 512, 0, stream>>>(src, dst, A0, csr_off, csr_eid, logA0);
    prep_split<<<4096, 256, 0, stream>>>(H, Hh, Hl, (int)(nX / 4));
    prep_split<<<64, 256, 0, stream>>>(W_lin, Wlh, Wll, D_ * D_ / 4);
    prep_split<<<64, 256, 0, stream>>>(W_val, Wvh, Wvl, D_ * D_ / 4);

    gemm_bf16s<true,  false><<<1024, 256, 0, stream>>>(Hh, Hl, Wlh, Wll, Xq);
    gemm_bf16s<false, true ><<<1024, 256, 0, stream>>>(Hh, Hl, Wvh, Wvl, Xvb);

    fused_edge_agg<<<4096, 256, 0, stream>>>(Xq, Xvb, src, dst, a, logA0,
                                             csr_off, csr_eid, Yh, Yl);

    prep_split<<<64, 256, 0, stream>>>(W_out, Wouth, Woutl, D_ * D_ / 4);
    gemm_bf16s<true,  false><<<1024, 256, 0, stream>>>(Yh, Yl, Wouth, Woutl, (float*)d_out);
}